// Round 1
// baseline (305.546 us; speedup 1.0000x reference)
//
#include <hip/hip_runtime.h>
#include <cstdint>

#define NROWS 16384
#define DD 128
#define KK 64
#define CH 16

// ---------------- k1: per-row distances / argmin / log-softmax / quantize ----------------
__global__ __launch_bounds__(256) void vq_k1(
    const float* __restrict__ x, const float* __restrict__ emb,
    float* __restrict__ qout, float* __restrict__ quant,
    float* __restrict__ ghist, double* __restrict__ gmse)
{
  __shared__ float Et4[32][64][4];   // Et4[g][k][j] = emb[k][4g+j]
  __shared__ float Epl[64][128];
  __shared__ float xs[4][4][128];    // [wave][row][d]
  __shared__ float lhist[64];
  const int tid = threadIdx.x;
  const int w = tid >> 6, lane = tid & 63;

  for (int i = tid; i < 2048; i += 256) {
    float4 v = ((const float4*)emb)[i];
    int k = i >> 5;
    int g = i & 31;
    *(float4*)&Epl[k][g << 2] = v;
    *(float4*)&Et4[g][k][0] = v;
  }
  if (tid < 64) lhist[tid] = 0.0f;
  __syncthreads();

  double esq = 0.0;
  #pragma unroll
  for (int g = 0; g < 32; ++g) {
    float4 e = *(float4*)&Et4[g][lane][0];
    esq += (double)e.x * e.x + (double)e.y * e.y + (double)e.z * e.z + (double)e.w * e.w;
  }

  double msea = 0.0;
  const int gw = blockIdx.x * 4 + w;

  for (int it = 0; it < 4; ++it) {
    const int grp = gw + it * 1024;     // 4096 groups of 4 rows
    const int r0 = grp << 2;
    const float4* xg = (const float4*)(x + (size_t)r0 * DD);
    float4 v0 = xg[lane];
    float4 v1 = xg[lane + 64];
    *(float4*)&xs[w][lane >> 5][(lane & 31) << 2] = v0;
    *(float4*)&xs[w][2 + (lane >> 5)][(lane & 31) << 2] = v1;
    __syncthreads();

    double acc[4] = {0.0, 0.0, 0.0, 0.0};
    for (int g = 0; g < 32; ++g) {
      float4 e = *(float4*)&Et4[g][lane][0];
      double ex = e.x, ey = e.y, ez = e.z, ew = e.w;
      #pragma unroll
      for (int rr = 0; rr < 4; ++rr) {
        float4 xv = *(float4*)&xs[w][rr][g << 2];
        acc[rr] += ex * xv.x + ey * xv.y + ez * xv.z + ew * xv.w;
      }
    }

    #pragma unroll
    for (int rr = 0; rr < 4; ++rr) {
      const int row = r0 + rr;
      // xsq is uniform across k: drop it (cancels in argmin and log_softmax)
      double dist = esq - 2.0 * acc[rr];
      double v = dist; int bi = lane;
      #pragma unroll
      for (int off = 32; off; off >>= 1) {
        double ov = __shfl_xor(v, off);
        int oi = __shfl_xor(bi, off);
        if (ov < v || (ov == v && oi < bi)) { v = ov; bi = oi; }
      }
      double mx = dist;
      #pragma unroll
      for (int off = 32; off; off >>= 1) {
        double om = __shfl_xor(mx, off);
        mx = fmax(mx, om);
      }
      double sh = dist - mx;
      double e2 = exp(sh);
      double ss = e2;
      #pragma unroll
      for (int off = 32; off; off >>= 1) ss += __shfl_xor(ss, off);
      qout[(size_t)row * KK + lane] = (float)(sh - log(ss));

      float e0 = Epl[bi][lane], e1 = Epl[bi][64 + lane];
      float x0 = xs[w][rr][lane], x1 = xs[w][rr][64 + lane];
      quant[(size_t)row * DD + lane]      = x0 + (e0 - x0);
      quant[(size_t)row * DD + 64 + lane] = x1 + (e1 - x1);
      double d0 = (double)e0 - (double)x0, d1 = (double)e1 - (double)x1;
      msea += d0 * d0 + d1 * d1;
      if (lane == 0) atomicAdd(&lhist[bi], 1.0f);
    }
  }
  #pragma unroll
  for (int off = 32; off; off >>= 1) msea += __shfl_down(msea, off);
  if (lane == 0) atomicAdd(gmse, msea);
  __syncthreads();
  if (tid < 64) atomicAdd(&ghist[tid], lhist[tid]);
}

// ---------------- k2: C[k,m,n] partials, 8x8 register tiles ----------------
__global__ __launch_bounds__(256) void vq_k2(const float* __restrict__ q, float* __restrict__ cpart)
{
  __shared__ float tile[66][64];
  const int bx = blockIdx.x;
  const int kg = bx >> 4, chunk = bx & 15;
  const int tid = threadIdx.x;
  const int w = tid >> 6, lane = tid & 63;
  const int k = (kg << 2) + w;
  const int tm = lane >> 3, tn = lane & 7;
  float c[8][8];
  #pragma unroll
  for (int i = 0; i < 8; ++i)
    #pragma unroll
    for (int j = 0; j < 8; ++j) c[i][j] = 0.0f;

  const int base = chunk << 10;
  for (int t0 = base; t0 < base + 1024; t0 += 64) {
    __syncthreads();
    for (int i = tid; i < 66 * 16; i += 256) {
      int rr = i >> 4, c4 = (i & 15) << 2;
      int r = t0 + rr;
      float4 v = make_float4(0.f, 0.f, 0.f, 0.f);
      if (r < NROWS) v = *(const float4*)(q + (size_t)r * KK + c4);
      *(float4*)&tile[rr][c4] = v;
    }
    __syncthreads();
    #pragma unroll 4
    for (int tt = 0; tt < 64; ++tt) {
      int r = t0 + tt;
      if ((r & 4095) > 4093) continue;   // triples must stay within a batch
      float q0 = tile[tt][k];
      float4 a0 = *(float4*)&tile[tt + 1][tm << 3];
      float4 a1 = *(float4*)&tile[tt + 1][(tm << 3) + 4];
      float4 b0 = *(float4*)&tile[tt + 2][tn << 3];
      float4 b1 = *(float4*)&tile[tt + 2][(tn << 3) + 4];
      float pp[8] = {q0*a0.x, q0*a0.y, q0*a0.z, q0*a0.w, q0*a1.x, q0*a1.y, q0*a1.z, q0*a1.w};
      float bb[8] = {b0.x, b0.y, b0.z, b0.w, b1.x, b1.y, b1.z, b1.w};
      #pragma unroll
      for (int i = 0; i < 8; ++i)
        #pragma unroll
        for (int j = 0; j < 8; ++j) c[i][j] += pp[i] * bb[j];
    }
  }
  float* outp = cpart + (((size_t)(chunk << 6) + (size_t)k) << 12);
  #pragma unroll
  for (int i = 0; i < 8; ++i) {
    #pragma unroll
    for (int j = 0; j < 8; j += 4) {
      float4 v = make_float4(c[i][j], c[i][j+1], c[i][j+2], c[i][j+3]);
      *(float4*)&outp[((tm << 3) + i) * 64 + (tn << 3) + j] = v;
    }
  }
}

// ---------------- k3: C_pair partials ----------------
__global__ __launch_bounds__(64) void vq_k3(const float* __restrict__ q, float* __restrict__ ppart)
{
  __shared__ float tile[65][64];
  const int chunk = blockIdx.x;    // 0..63
  const int lane = threadIdx.x;
  const int tm = lane >> 3, tn = lane & 7;
  float c[8][8];
  #pragma unroll
  for (int i = 0; i < 8; ++i)
    #pragma unroll
    for (int j = 0; j < 8; ++j) c[i][j] = 0.0f;

  const int base = chunk << 8;
  for (int t0 = base; t0 < base + 256; t0 += 64) {
    __syncthreads();
    for (int i = lane; i < 65 * 16; i += 64) {
      int rr = i >> 4, c4 = (i & 15) << 2;
      int r = t0 + rr;
      float4 v = make_float4(0.f, 0.f, 0.f, 0.f);
      if (r < NROWS) v = *(const float4*)(q + (size_t)r * KK + c4);
      *(float4*)&tile[rr][c4] = v;
    }
    __syncthreads();
    #pragma unroll 4
    for (int tt = 0; tt < 64; ++tt) {
      int r = t0 + tt;
      if ((r & 4095) > 4094) continue;   // pairs must stay within a batch
      float4 a0 = *(float4*)&tile[tt][tm << 3];
      float4 a1 = *(float4*)&tile[tt][(tm << 3) + 4];
      float4 b0 = *(float4*)&tile[tt + 1][tn << 3];
      float4 b1 = *(float4*)&tile[tt + 1][(tn << 3) + 4];
      float aa[8] = {a0.x, a0.y, a0.z, a0.w, a1.x, a1.y, a1.z, a1.w};
      float bb[8] = {b0.x, b0.y, b0.z, b0.w, b1.x, b1.y, b1.z, b1.w};
      #pragma unroll
      for (int i = 0; i < 8; ++i)
        #pragma unroll
        for (int j = 0; j < 8; ++j) c[i][j] += aa[i] * bb[j];
    }
  }
  float* outp = ppart + (size_t)chunk * 4096;
  #pragma unroll
  for (int i = 0; i < 8; ++i) {
    #pragma unroll
    for (int j = 0; j < 8; j += 4) {
      float4 v = make_float4(c[i][j], c[i][j+1], c[i][j+2], c[i][j+3]);
      *(float4*)&outp[((tm << 3) + i) * 64 + (tn << 3) + j] = v;
    }
  }
}

// ---------------- k4: reduce partials ----------------
__global__ __launch_bounds__(256) void vq_k4(const float* __restrict__ cpart, const float* __restrict__ ppart,
                                             float* __restrict__ C, float* __restrict__ Cpair)
{
  int i = blockIdx.x * 256 + threadIdx.x;
  if (i < 262144) {
    float s = 0.f;
    #pragma unroll
    for (int cc = 0; cc < CH; ++cc) s += cpart[(size_t)cc * 262144 + i];
    C[i] = s;
  } else {
    int j = i - 262144;
    float s = 0.f;
    #pragma unroll 8
    for (int cc = 0; cc < 64; ++cc) s += ppart[(size_t)cc * 4096 + j];
    Cpair[j] = s;
  }
}

// ---------------- k5a: H_cond rows ----------------
__global__ __launch_bounds__(256) void vq_k5a(const float* __restrict__ C, float* __restrict__ hcond)
{
  int p = blockIdx.x * 256 + threadIdx.x;   // 0..4095 = k*64+m
  const float* row = C + (size_t)p * 64;
  float rs = 0.f;
  #pragma unroll
  for (int n = 0; n < 64; ++n) rs += row[n] + 0.001f;
  float denom = rs + 1e-8f;
  float h = 0.f;
  #pragma unroll 8
  for (int n = 0; n < 64; ++n) {
    float T = (row[n] + 0.001f) / denom;
    h -= T * logf(T + 1e-8f);
  }
  hcond[p] = h;
}

// ---------------- k5b: final scalar ----------------
__global__ __launch_bounds__(256) void vq_k5b(const float* __restrict__ Cpair, const float* __restrict__ hcond,
                                              const float* __restrict__ ghist, const double* __restrict__ gmse,
                                              const float* __restrict__ prior, float* __restrict__ out_loss)
{
  __shared__ float red[8];
  const int tid = threadIdx.x;
  float ts = 0.f;
  for (int p = tid; p < 4096; p += 256) ts += Cpair[p];
  #pragma unroll
  for (int off = 32; off; off >>= 1) ts += __shfl_down(ts, off);
  if ((tid & 63) == 0) red[tid >> 6] = ts;
  __syncthreads();
  float total = red[0] + red[1] + red[2] + red[3];
  float invtot = 1.0f / (total + 1e-8f);
  float h2 = 0.f;
  for (int p = tid; p < 4096; p += 256) h2 += Cpair[p] * hcond[p];
  h2 *= invtot;
  #pragma unroll
  for (int off = 32; off; off >>= 1) h2 += __shfl_down(h2, off);
  __syncthreads();
  if ((tid & 63) == 0) red[4 + (tid >> 6)] = h2;
  __syncthreads();
  if (tid == 0) {
    float H2 = red[4] + red[5] + red[6] + red[7];
    float kl = 0.f;
    for (int k = 0; k < 64; ++k) {
      float pk = ghist[k] * (1.0f / 16384.0f);
      kl += pk * (logf(pk + 1e-10f) - logf(prior[k] + 1e-10f));
    }
    float mse = (float)(gmse[0] * (1.0 / (16384.0 * 128.0)));
    out_loss[0] = 1.25f * mse + 1.0f * kl + 0.1f * H2;
  }
}

extern "C" void kernel_launch(void* const* d_in, const int* in_sizes, int n_in,
                              void* d_out, int out_size, void* d_ws, size_t ws_size,
                              hipStream_t stream)
{
  (void)in_sizes; (void)n_in; (void)out_size; (void)ws_size;
  const float* x     = (const float*)d_in[0];
  const float* emb   = (const float*)d_in[2];
  const float* prior = (const float*)d_in[3];
  float* quant    = (float*)d_out;
  float* loss_out = (float*)d_out + 2097152;

  char* ws = (char*)d_ws;
  float*  q     = (float*)(ws);                  // 16384*64*4   = 4,194,304 B
  float*  cpart = (float*)(ws + 4194304);        // 16*64*4096*4 = 16,777,216 B
  float*  ppart = (float*)(ws + 20971520);       // 64*4096*4    = 1,048,576 B
  float*  C     = (float*)(ws + 22020096);       // 262144*4     = 1,048,576 B
  float*  Cpair = (float*)(ws + 23068672);       // 16,384 B
  float*  hcond = (float*)(ws + 23085056);       // 16,384 B
  double* gmse  = (double*)(ws + 23101440);      // 8 B
  float*  ghist = (float*)(ws + 23101448);       // 256 B

  hipMemsetAsync(ws + 23101440, 0, 8 + 256, stream);
  vq_k1<<<256, 256, 0, stream>>>(x, emb, q, quant, ghist, gmse);
  vq_k2<<<256, 256, 0, stream>>>(q, cpart);
  vq_k3<<<64, 64, 0, stream>>>(q, ppart);
  vq_k4<<<1040, 256, 0, stream>>>(cpart, ppart, C, Cpair);
  vq_k5a<<<16, 256, 0, stream>>>(C, hcond);
  vq_k5b<<<1, 256, 0, stream>>>(Cpair, hcond, ghist, gmse, prior, loss_out);
}

// Round 2
// 123.814 us; speedup vs baseline: 2.4678x; 2.4678x over previous
//
#include <hip/hip_runtime.h>
#include <cstdint>

#define NROWS 16384

typedef __attribute__((ext_vector_type(8))) short short8;
typedef __attribute__((ext_vector_type(4))) float f32x4;

static __device__ __forceinline__ float b2f(short s){
  union{unsigned u; float f;} z; z.u = ((unsigned)(unsigned short)s) << 16; return z.f;
}
static __device__ __forceinline__ unsigned short f2b(float v){
  union{float f; unsigned u;} z; z.f = v;
  z.u += 0x7fffu + ((z.u >> 16) & 1u);
  return (unsigned short)(z.u >> 16);
}

// ---------------- k1: per-row distances / argmin / log-softmax / quantize ----------------
__global__ __launch_bounds__(256) void vq_k1(
    const float* __restrict__ x, const float* __restrict__ emb,
    float* __restrict__ qout, float* __restrict__ quant,
    float* __restrict__ ghist2, double* __restrict__ gmse2)
{
  __shared__ float Et4[32][64][4];   // Et4[g][k][j] = emb[k][4g+j]
  __shared__ float xs[4][4][128];    // [wave][row][d]
  __shared__ float lhist[64];
  __shared__ double mred[4];
  const int tid = threadIdx.x;
  const int w = tid >> 6, lane = tid & 63;

  for (int i = tid; i < 2048; i += 256) {
    float4 v = ((const float4*)emb)[i];
    *(float4*)&Et4[i & 31][i >> 5][0] = v;
  }
  if (tid < 64) lhist[tid] = 0.0f;
  __syncthreads();

  double esq = 0.0;
  #pragma unroll
  for (int g = 0; g < 32; ++g) {
    float4 e = *(float4*)&Et4[g][lane][0];
    esq += (double)e.x * e.x + (double)e.y * e.y + (double)e.z * e.z + (double)e.w * e.w;
  }

  const int grp = blockIdx.x * 4 + w;     // 0..4095
  const int r0 = grp << 2;
  const float4* xg = (const float4*)(x + (size_t)r0 * 128);
  float4 v0 = xg[lane];
  float4 v1 = xg[lane + 64];
  *(float4*)&xs[w][lane >> 5][(lane & 31) << 2] = v0;
  *(float4*)&xs[w][2 + (lane >> 5)][(lane & 31) << 2] = v1;
  __syncthreads();

  double acc[4] = {0.0, 0.0, 0.0, 0.0};
  for (int g = 0; g < 32; ++g) {
    float4 e = *(float4*)&Et4[g][lane][0];
    double ex = e.x, ey = e.y, ez = e.z, ew = e.w;
    #pragma unroll
    for (int rr = 0; rr < 4; ++rr) {
      float4 xv = *(float4*)&xs[w][rr][g << 2];
      acc[rr] += ex * xv.x + ey * xv.y + ez * xv.z + ew * xv.w;
    }
  }

  double msea = 0.0;
  #pragma unroll
  for (int rr = 0; rr < 4; ++rr) {
    const int row = r0 + rr;
    double dist = esq - 2.0 * acc[rr];   // xsq dropped: cancels in argmin & log_softmax
    double v = dist; int bi = lane;
    #pragma unroll
    for (int off = 32; off; off >>= 1) {
      double ov = __shfl_xor(v, off);
      int oi = __shfl_xor(bi, off);
      if (ov < v || (ov == v && oi < bi)) { v = ov; bi = oi; }
    }
    float d32 = (float)dist;
    float mx = d32;
    #pragma unroll
    for (int off = 32; off; off >>= 1) mx = fmaxf(mx, __shfl_xor(mx, off));
    float sh = d32 - mx;
    float ss = expf(sh);
    #pragma unroll
    for (int off = 32; off; off >>= 1) ss += __shfl_xor(ss, off);
    qout[(size_t)row * 64 + lane] = sh - logf(ss);

    float e0 = emb[bi * 128 + lane], e1 = emb[bi * 128 + 64 + lane];
    float x0 = xs[w][rr][lane], x1 = xs[w][rr][64 + lane];
    quant[(size_t)row * 128 + lane]      = x0 + (e0 - x0);
    quant[(size_t)row * 128 + 64 + lane] = x1 + (e1 - x1);
    double d0 = (double)e0 - (double)x0, d1 = (double)e1 - (double)x1;
    msea += d0 * d0 + d1 * d1;
    if (lane == 0) atomicAdd(&lhist[bi], 1.0f);
  }
  #pragma unroll
  for (int off = 32; off; off >>= 1) msea += __shfl_down(msea, off);
  if (lane == 0) mred[w] = msea;
  __syncthreads();
  if (tid == 0) atomicAdd(&gmse2[blockIdx.x & 31], mred[0] + mred[1] + mred[2] + mred[3]);
  if (tid < 64) atomicAdd(&ghist2[((blockIdx.x & 31) << 6) + tid], lhist[tid]);
}

// ---------------- k1b: build 3 shifted, transposed, swizzled bf16 images ----------------
// qbf[tile c][s][kk][tt] bf16, 24576 B per tile. Image s holds q[64c+tt+s][kk],
// zeroed where the base t is invalid for the shifted use (masks batch boundaries).
__global__ __launch_bounds__(256) void vq_k1b(const float* __restrict__ q, unsigned short* __restrict__ qbf)
{
  __shared__ float tq[66][65];
  const int c = blockIdx.x, tid = threadIdx.x;
  for (int i = tid; i < 1056; i += 256) {
    int r = i >> 4, c4 = (i & 15) << 2;
    int t = c * 64 + r;
    float4 v = make_float4(0.f, 0.f, 0.f, 0.f);
    if (t < NROWS) v = *(const float4*)(q + (size_t)t * 64 + c4);
    tq[r][c4 + 0] = v.x; tq[r][c4 + 1] = v.y; tq[r][c4 + 2] = v.z; tq[r][c4 + 3] = v.w;
  }
  __syncthreads();
  char* out0 = (char*)qbf + (size_t)c * 24576;
  for (int idx = tid; idx < 1536; idx += 256) {
    int s = idx >> 9;            // 0..2
    int kk = (idx >> 3) & 63;
    int t8 = (idx & 7) << 3;
    unsigned short h[8] __attribute__((aligned(16)));
    #pragma unroll
    for (int j = 0; j < 8; ++j) {
      int tt = t8 + j;
      int t = c * 64 + tt;
      float val = tq[tt + s][kk];
      bool zero = (s == 1 && (t & 4095) == 4095) || (s == 2 && (t & 4095) >= 4094);
      if (zero) val = 0.f;
      h[j] = f2b(val);
    }
    int off = s * 8192 + kk * 128 + ((t8 * 2) ^ ((kk & 7) << 4));
    *(uint4*)(out0 + off) = *(const uint4*)h;
  }
}

// ---------------- k2: C[k,m,n] via MFMA. A = q0[.,k]*q1, B = q2 ----------------
__global__ __launch_bounds__(256, 2) void vq_k2(const unsigned short* __restrict__ qbf, float* __restrict__ C)
{
  __shared__ uint4 lds4[3072];       // 2 buffers x 24576 B
  char* ldsB = (char*)lds4;
  const int bx = blockIdx.x;
  const int chunk = bx & 31, kg = bx >> 5;
  const int tid = threadIdx.x;
  const int w = tid >> 6, lane = tid & 63;
  const int k = kg * 4 + w;

  f32x4 acc[4][4];
  #pragma unroll
  for (int i = 0; i < 4; ++i)
    #pragma unroll
    for (int j = 0; j < 4; ++j) acc[i][j] = (f32x4)(0.f);

  const int ct0 = chunk * 8;
  const uint4* src0 = (const uint4*)(qbf) ;

  // prologue: stage tile ct0 into buf 0
  {
    const uint4* src = (const uint4*)((const char*)qbf + (size_t)ct0 * 24576);
    uint4* dst = (uint4*)ldsB;
    #pragma unroll
    for (int it = 0; it < 6; ++it) dst[it * 256 + tid] = src[it * 256 + tid];
  }
  __syncthreads();

  int cur = 0;
  for (int i = 0; i < 8; ++i) {
    uint4 tmp0, tmp1, tmp2, tmp3, tmp4, tmp5;
    const bool pf = (i < 7);
    if (pf) {
      const uint4* src = (const uint4*)((const char*)qbf + (size_t)(ct0 + i + 1) * 24576);
      tmp0 = src[0 * 256 + tid]; tmp1 = src[1 * 256 + tid]; tmp2 = src[2 * 256 + tid];
      tmp3 = src[3 * 256 + tid]; tmp4 = src[4 * 256 + tid]; tmp5 = src[5 * 256 + tid];
    }
    // compute on buf cur
    {
      const char* base = ldsB + cur * 24576;
      #pragma unroll
      for (int s = 0; s < 2; ++s) {
        const int tb = (s << 6) | ((lane >> 4) << 4);
        const int swz = (lane & 7) << 4;
        short8 q0v = *(const short8*)(base + (k << 7) + (tb ^ ((k & 7) << 4)));
        float q0f[8];
        #pragma unroll
        for (int j = 0; j < 8; ++j) q0f[j] = b2f(q0v[j]);
        short8 Bv[4];
        #pragma unroll
        for (int nb = 0; nb < 4; ++nb)
          Bv[nb] = *(const short8*)(base + 16384 + ((nb * 16 + (lane & 15)) << 7) + (tb ^ swz));
        #pragma unroll
        for (int mb = 0; mb < 4; ++mb) {
          short8 q1v = *(const short8*)(base + 8192 + ((mb * 16 + (lane & 15)) << 7) + (tb ^ swz));
          short8 av;
          #pragma unroll
          for (int j = 0; j < 8; ++j) av[j] = (short)f2b(q0f[j] * b2f(q1v[j]));
          #pragma unroll
          for (int nb = 0; nb < 4; ++nb)
            acc[mb][nb] = __builtin_amdgcn_mfma_f32_16x16x32_bf16(av, Bv[nb], acc[mb][nb], 0, 0, 0);
        }
      }
    }
    if (pf) {
      uint4* dst = (uint4*)(ldsB + (cur ^ 1) * 24576);
      dst[0 * 256 + tid] = tmp0; dst[1 * 256 + tid] = tmp1; dst[2 * 256 + tid] = tmp2;
      dst[3 * 256 + tid] = tmp3; dst[4 * 256 + tid] = tmp4; dst[5 * 256 + tid] = tmp5;
    }
    __syncthreads();
    cur ^= 1;
  }

  const int m0 = (lane >> 4) << 2, n0 = lane & 15;
  float* Ck = C + ((size_t)k << 12);
  #pragma unroll
  for (int mb = 0; mb < 4; ++mb)
    #pragma unroll
    for (int nb = 0; nb < 4; ++nb)
      #pragma unroll
      for (int r = 0; r < 4; ++r)
        atomicAdd(&Ck[(mb * 16 + m0 + r) * 64 + nb * 16 + n0], acc[mb][nb][r]);
}

// ---------------- k3: C_pair via MFMA, fragments straight from global ----------------
__global__ __launch_bounds__(256) void vq_k3(const unsigned short* __restrict__ qbf, float* __restrict__ Cpair)
{
  const int bx = blockIdx.x;           // 0..31
  const int tid = threadIdx.x;
  const int w = tid >> 6, lane = tid & 63;
  f32x4 acc[4][4];
  #pragma unroll
  for (int i = 0; i < 4; ++i)
    #pragma unroll
    for (int j = 0; j < 4; ++j) acc[i][j] = (f32x4)(0.f);

  for (int ii = 0; ii < 2; ++ii) {
    const int ct = bx * 8 + w * 2 + ii;
    const char* tile = (const char*)qbf + (size_t)ct * 24576;
    #pragma unroll
    for (int s = 0; s < 2; ++s) {
      const int tb = (s << 6) | ((lane >> 4) << 4);
      const int swz = (lane & 7) << 4;
      short8 Av[4], Bv[4];
      #pragma unroll
      for (int mb = 0; mb < 4; ++mb)
        Av[mb] = *(const short8*)(tile + ((mb * 16 + (lane & 15)) << 7) + (tb ^ swz));
      #pragma unroll
      for (int nb = 0; nb < 4; ++nb)
        Bv[nb] = *(const short8*)(tile + 8192 + ((nb * 16 + (lane & 15)) << 7) + (tb ^ swz));
      #pragma unroll
      for (int mb = 0; mb < 4; ++mb)
        #pragma unroll
        for (int nb = 0; nb < 4; ++nb)
          acc[mb][nb] = __builtin_amdgcn_mfma_f32_16x16x32_bf16(Av[mb], Bv[nb], acc[mb][nb], 0, 0, 0);
    }
  }
  const int m0 = (lane >> 4) << 2, n0 = lane & 15;
  #pragma unroll
  for (int mb = 0; mb < 4; ++mb)
    #pragma unroll
    for (int nb = 0; nb < 4; ++nb)
      #pragma unroll
      for (int r = 0; r < 4; ++r)
        atomicAdd(&Cpair[(mb * 16 + m0 + r) * 64 + nb * 16 + n0], acc[mb][nb][r]);
}

// ---------------- k5a: H_cond rows ----------------
__global__ __launch_bounds__(256) void vq_k5a(const float* __restrict__ C, float* __restrict__ hcond)
{
  int p = blockIdx.x * 256 + threadIdx.x;   // 0..4095 = k*64+m
  const float* row = C + (size_t)p * 64;
  float rs = 0.f;
  #pragma unroll
  for (int n = 0; n < 64; ++n) rs += row[n] + 0.001f;
  float denom = rs + 1e-8f;
  float h = 0.f;
  #pragma unroll 8
  for (int n = 0; n < 64; ++n) {
    float T = (row[n] + 0.001f) / denom;
    h -= T * logf(T + 1e-8f);
  }
  hcond[p] = h;
}

// ---------------- k5b: final scalar ----------------
__global__ __launch_bounds__(256) void vq_k5b(const float* __restrict__ Cpair, const float* __restrict__ hcond,
                                              const float* __restrict__ ghist2, const double* __restrict__ gmse2,
                                              const float* __restrict__ prior, float* __restrict__ out_loss)
{
  __shared__ float red[8];
  __shared__ float hsum[64];
  __shared__ double msh;
  const int tid = threadIdx.x;
  if (tid < 64) {
    float s = 0.f;
    for (int c2 = 0; c2 < 32; ++c2) s += ghist2[(c2 << 6) + tid];
    hsum[tid] = s;
  }
  if (tid == 64) {
    double s = 0.0;
    for (int c2 = 0; c2 < 32; ++c2) s += gmse2[c2];
    msh = s;
  }
  float ts = 0.f, hh = 0.f;
  for (int p = tid; p < 4096; p += 256) {
    float cp = Cpair[p];
    ts += cp;
    hh += cp * hcond[p];
  }
  #pragma unroll
  for (int off = 32; off; off >>= 1) {
    ts += __shfl_down(ts, off);
    hh += __shfl_down(hh, off);
  }
  if ((tid & 63) == 0) { red[tid >> 6] = ts; red[4 + (tid >> 6)] = hh; }
  __syncthreads();
  if (tid == 0) {
    float total = red[0] + red[1] + red[2] + red[3];
    float H2 = (red[4] + red[5] + red[6] + red[7]) / (total + 1e-8f);
    float kl = 0.f;
    for (int kq = 0; kq < 64; ++kq) {
      float pk = hsum[kq] * (1.0f / 16384.0f);
      kl += pk * (logf(pk + 1e-10f) - logf(prior[kq] + 1e-10f));
    }
    float mse = (float)(msh * (1.0 / (16384.0 * 128.0)));
    out_loss[0] = 1.25f * mse + kl + 0.1f * H2;
  }
}

extern "C" void kernel_launch(void* const* d_in, const int* in_sizes, int n_in,
                              void* d_out, int out_size, void* d_ws, size_t ws_size,
                              hipStream_t stream)
{
  (void)in_sizes; (void)n_in; (void)out_size; (void)ws_size;
  const float* x     = (const float*)d_in[0];
  const float* emb   = (const float*)d_in[2];
  const float* prior = (const float*)d_in[3];
  float* quant    = (float*)d_out;
  float* loss_out = (float*)d_out + 2097152;

  char* ws = (char*)d_ws;
  float*          q      = (float*)(ws);                      // 4,194,304 B
  unsigned short* qbf    = (unsigned short*)(ws + 4194304);   // 256*24576 = 6,291,456 B
  float*          C      = (float*)(ws + 10485760);           // 1,048,576 B
  float*          Cpair  = (float*)(ws + 11534336);           // 16,384 B
  float*          hcond  = (float*)(ws + 11550720);           // 16,384 B
  double*         gmse2  = (double*)(ws + 11567104);          // 256 B
  float*          ghist2 = (float*)(ws + 11567360);           // 8,192 B

  hipMemsetAsync(ws + 10485760, 0, 1089792, stream);
  vq_k1 <<<1024, 256, 0, stream>>>(x, emb, q, quant, ghist2, gmse2);
  vq_k1b<<<256, 256, 0, stream>>>(q, qbf);
  vq_k2 <<<512, 256, 0, stream>>>(qbf, C);
  vq_k3 <<<32, 256, 0, stream>>>(qbf, Cpair);
  vq_k5a<<<16, 256, 0, stream>>>(C, hcond);
  vq_k5b<<<1, 256, 0, stream>>>(Cpair, hcond, ghist2, gmse2, prior, loss_out);
}

// Round 3
// 97.685 us; speedup vs baseline: 3.1279x; 1.2675x over previous
//
#include <hip/hip_runtime.h>
#include <cstdint>

#define NROWS 16384

typedef __attribute__((ext_vector_type(4))) float f32x4;
typedef _Float16 half8 __attribute__((ext_vector_type(8)));

static __device__ __forceinline__ void gl_lds16(const void* g, void* l) {
  __builtin_amdgcn_global_load_lds(
      (const __attribute__((address_space(1))) unsigned int*)g,
      (__attribute__((address_space(3))) unsigned int*)l, 16, 0, 0);
}

// ---------------- k1: distances/argmin/softmax/quantize + fp16 image build ----------------
// Block c owns rows 64c..64c+65 (2 halo rows recomputed); emits 3 shifted transposed
// swizzled fp16 images (24576 B per tile) consumed by k2/k3.
__global__ __launch_bounds__(512) void vq_k1(
    const float* __restrict__ x, const float* __restrict__ emb,
    unsigned short* __restrict__ qbf, float* __restrict__ quant,
    float* __restrict__ ghist2, double* __restrict__ gmse2)
{
  __shared__ float Et4[32][64][4];   // Et4[g][k][j] = emb[k][4g+j]
  __shared__ float xs[8][4][128];
  __shared__ float qlds[66][65];
  __shared__ float lhist[64];
  __shared__ double mred[8];
  const int tid = threadIdx.x;
  const int w = tid >> 6, lane = tid & 63;
  const int c = blockIdx.x;

  for (int i = tid; i < 2048; i += 512) {
    float4 v = ((const float4*)emb)[i];
    *(float4*)&Et4[i & 31][i >> 5][0] = v;
  }
  if (tid < 64) lhist[tid] = 0.0f;
  __syncthreads();

  double esq = 0.0;
  for (int g = 0; g < 32; ++g) {
    float4 e = *(float4*)&Et4[g][lane][0];
    esq += (double)e.x*e.x + (double)e.y*e.y + (double)e.z*e.z + (double)e.w*e.w;
  }
  const float esqf = (float)esq;

  double msea = 0.0;

  for (int it = 0; it < 3; ++it) {
    const int lr0 = it*32 + w*4;
    const bool act = (it < 2) || (w == 0);
    if (!act) continue;
    const int nr = (it < 2) ? 4 : 2;
    const int r0 = c*64 + lr0;
    const float4* xg = (const float4*)(x + (size_t)r0 * 128);
    if (it < 2) {
      float4 v0 = xg[lane], v1 = xg[lane + 64];
      *(float4*)&xs[w][lane>>5][(lane&31)<<2] = v0;
      *(float4*)&xs[w][2+(lane>>5)][(lane&31)<<2] = v1;
    } else {
      int rr = lane >> 5;
      float4 v0 = make_float4(0.f,0.f,0.f,0.f);
      if (r0 + rr < NROWS) v0 = xg[lane];
      *(float4*)&xs[w][rr][(lane&31)<<2] = v0;
    }

    float accf[4] = {0.f,0.f,0.f,0.f};
    for (int g = 0; g < 32; ++g) {
      float4 e = *(float4*)&Et4[g][lane][0];
      #pragma unroll
      for (int rr = 0; rr < 4; ++rr) {
        float4 xv = *(float4*)&xs[w][rr][g<<2];
        accf[rr] += e.x*xv.x + e.y*xv.y + e.z*xv.z + e.w*xv.w;
      }
    }

    for (int rr = 0; rr < nr; ++rr) {
      float dist = esqf - 2.0f*accf[rr];
      float mx = dist;
      #pragma unroll
      for (int off = 32; off; off >>= 1) mx = fmaxf(mx, __shfl_xor(mx, off));
      float sh = dist - mx;
      float ss = expf(sh);
      #pragma unroll
      for (int off = 32; off; off >>= 1) ss += __shfl_xor(ss, off);
      qlds[lr0 + rr][lane] = sh - logf(ss);

      if (it < 2) {
        // top-2 argmin butterfly (f32) with f64 fallback on near-tie
        float m1 = dist, m2 = 3.4e38f; int i1 = lane;
        #pragma unroll
        for (int off = 32; off; off >>= 1) {
          float om1 = __shfl_xor(m1, off);
          int   oi1 = __shfl_xor(i1, off);
          float om2 = __shfl_xor(m2, off);
          float nm2 = fminf(m2, om2);
          if (om1 < m1 || (om1 == m1 && oi1 < i1)) { nm2 = fminf(nm2, m1); m1 = om1; i1 = oi1; }
          else nm2 = fminf(nm2, om1);
          m2 = nm2;
        }
        int bi = i1;
        if (m2 - m1 < 1e-4f) {
          double a64 = 0.0;
          for (int g = 0; g < 32; ++g) {
            float4 e = *(float4*)&Et4[g][lane][0];
            float4 xv = *(float4*)&xs[w][rr][g<<2];
            a64 += (double)e.x*xv.x + (double)e.y*xv.y + (double)e.z*xv.z + (double)e.w*xv.w;
          }
          double v = esq - 2.0*a64; int b2 = lane;
          #pragma unroll
          for (int off = 32; off; off >>= 1) {
            double ov = __shfl_xor(v, off);
            int ob = __shfl_xor(b2, off);
            if (ov < v || (ov == v && ob < b2)) { v = ov; b2 = ob; }
          }
          bi = b2;
        }
        const int row = r0 + rr;
        float e0 = emb[bi*128 + lane], e1 = emb[bi*128 + 64 + lane];
        float x0 = xs[w][rr][lane], x1 = xs[w][rr][64 + lane];
        quant[(size_t)row*128 + lane]      = x0 + (e0 - x0);
        quant[(size_t)row*128 + 64 + lane] = x1 + (e1 - x1);
        double d0 = (double)e0 - x0, d1 = (double)e1 - x1;
        msea += d0*d0 + d1*d1;
        if (lane == 0) atomicAdd(&lhist[bi], 1.0f);
      }
    }
  }
  #pragma unroll
  for (int off = 32; off; off >>= 1) msea += __shfl_down(msea, off);
  if (lane == 0) mred[w] = msea;
  __syncthreads();
  if (tid == 0) {
    double s = 0.0;
    #pragma unroll
    for (int j = 0; j < 8; ++j) s += mred[j];
    atomicAdd(&gmse2[c & 15], s);
  }
  if (tid < 64) atomicAdd(&ghist2[((c & 15) << 6) + tid], lhist[tid]);

  // image build: im_s[kk][tt] = q[64c+tt+s][kk], fp16, XOR-swizzled, boundary-zeroed
  char* out0 = (char*)qbf + (size_t)c * 24576;
  for (int idx = tid; idx < 1536; idx += 512) {
    int s = idx >> 9, kk = (idx >> 3) & 63, t8 = (idx & 7) << 3;
    union { _Float16 h[8]; uint4 u; } pk;
    #pragma unroll
    for (int j = 0; j < 8; ++j) {
      int tt = t8 + j, t = c*64 + tt;
      float val = qlds[tt + s][kk];
      bool zero = (s == 1 && (t & 4095) == 4095) || (s == 2 && (t & 4095) >= 4094);
      pk.h[j] = (_Float16)(zero ? 0.0f : val);
    }
    *(uint4*)(out0 + s*8192 + kk*128 + ((t8*2) ^ ((kk & 7) << 4))) = pk.u;
  }
}

// ---------------- k2: C partials via fp16 MFMA, gload_lds dbuf, counted vmcnt ----------------
// grid 512 = kg(32) x chunk(16); waves: klocal(2) x s-half(2); 16 tiles per block.
__global__ __launch_bounds__(256) void vq_k2(const unsigned short* __restrict__ qbf, float* __restrict__ cpart)
{
  __shared__ __align__(16) char ldsbuf[32768];   // 2 x 16KB (im1+im2); reused as reduce buffer
  const int bx = blockIdx.x;
  const int kg = bx >> 4, chunk = bx & 15;
  const int tid = threadIdx.x;
  const int w = tid >> 6, lane = tid & 63;
  const int klocal = w >> 1, s = w & 1;
  const int k = kg*2 + klocal;

  f32x4 acc[4][4];
  #pragma unroll
  for (int i = 0; i < 4; ++i)
    #pragma unroll
    for (int j = 0; j < 4; ++j) acc[i][j] = (f32x4)(0.f);

  const char* qb = (const char*)qbf;
  const int t0 = chunk * 16;
  const int tb = (s << 6) | ((lane >> 4) << 4);
  const int swz = (lane & 7) << 4;
  const int swzk = (k & 7) << 4;

  // prologue: stage tile t0 (im1+im2) into buf0; prefetch q0 row
  {
    const char* src = qb + (size_t)t0 * 24576 + 8192 + w*4096 + lane*16;
    char* dst = ldsbuf + w*4096;
    #pragma unroll
    for (int j = 0; j < 4; ++j) gl_lds16(src + j*1024, dst + j*1024);
  }
  half8 q0v = *(const half8*)(qb + (size_t)t0 * 24576 + (k << 7) + (tb ^ swzk));

  int cur = 0;
  for (int i = 0; i < 16; ++i) {
    half8 q0n = q0v;
    if (i < 15) {
      const char* src = qb + (size_t)(t0+i+1) * 24576 + 8192 + w*4096 + lane*16;
      char* dst = ldsbuf + (cur^1)*16384 + w*4096;
      #pragma unroll
      for (int j = 0; j < 4; ++j) gl_lds16(src + j*1024, dst + j*1024);
      q0n = *(const half8*)(qb + (size_t)(t0+i+1) * 24576 + (k << 7) + (tb ^ swzk));
      asm volatile("s_waitcnt vmcnt(5)" ::: "memory");
    } else {
      asm volatile("s_waitcnt vmcnt(0)" ::: "memory");
    }
    __builtin_amdgcn_s_barrier();
    __builtin_amdgcn_sched_barrier(0);

    const char* base = ldsbuf + cur*16384;   // [0,8K)=im1, [8K,16K)=im2
    half8 Bv[4], q1v[4];
    #pragma unroll
    for (int nb = 0; nb < 4; ++nb)
      Bv[nb] = *(const half8*)(base + 8192 + ((nb*16 + (lane & 15)) << 7) + (tb ^ swz));
    #pragma unroll
    for (int mb = 0; mb < 4; ++mb)
      q1v[mb] = *(const half8*)(base + ((mb*16 + (lane & 15)) << 7) + (tb ^ swz));
    #pragma unroll
    for (int mb = 0; mb < 4; ++mb) {
      half8 av = q0v * q1v[mb];              // v_pk_mul_f16 x4
      #pragma unroll
      for (int nb = 0; nb < 4; ++nb)
        acc[mb][nb] = __builtin_amdgcn_mfma_f32_16x16x32_f16(av, Bv[nb], acc[mb][nb], 0, 0, 0);
    }
    __builtin_amdgcn_sched_barrier(0);
    __builtin_amdgcn_s_barrier();
    q0v = q0n;
    cur ^= 1;
  }

  __syncthreads();
  float* red = (float*)ldsbuf;               // 2 x 4096 f32
  const int m0 = (lane >> 4) << 2, n0 = lane & 15;
  if (s == 0) {
    #pragma unroll
    for (int mb = 0; mb < 4; ++mb)
      #pragma unroll
      for (int nb = 0; nb < 4; ++nb)
        #pragma unroll
        for (int r = 0; r < 4; ++r)
          red[klocal*4096 + (mb*16 + m0 + r)*64 + nb*16 + n0] = acc[mb][nb][r];
  }
  __syncthreads();
  if (s == 1) {
    #pragma unroll
    for (int mb = 0; mb < 4; ++mb)
      #pragma unroll
      for (int nb = 0; nb < 4; ++nb)
        #pragma unroll
        for (int r = 0; r < 4; ++r)
          red[klocal*4096 + (mb*16 + m0 + r)*64 + nb*16 + n0] += acc[mb][nb][r];
  }
  __syncthreads();
  float* dst = cpart + ((size_t)chunk*64 + (size_t)kg*2) * 4096;
  for (int i2 = tid; i2 < 2048; i2 += 256)
    ((f32x4*)dst)[i2] = ((const f32x4*)red)[i2];
}

// ---------------- k3: C_pair via fp16 MFMA + LDS reduce ----------------
__global__ __launch_bounds__(256) void vq_k3(const unsigned short* __restrict__ qbf, float* __restrict__ Cpair)
{
  __shared__ float red[4096];
  const int bx = blockIdx.x, tid = threadIdx.x;
  const int w = tid >> 6, lane = tid & 63;
  for (int i = tid; i < 4096; i += 256) red[i] = 0.f;

  f32x4 acc[4][4];
  #pragma unroll
  for (int i = 0; i < 4; ++i)
    #pragma unroll
    for (int j = 0; j < 4; ++j) acc[i][j] = (f32x4)(0.f);

  const char* tp = (const char*)qbf + (size_t)(4*bx + w) * 24576;
  #pragma unroll
  for (int s = 0; s < 2; ++s) {
    const int tb = (s << 6) | ((lane >> 4) << 4);
    const int swz = (lane & 7) << 4;
    half8 Av[4], Bv[4];
    #pragma unroll
    for (int mb = 0; mb < 4; ++mb)
      Av[mb] = *(const half8*)(tp + ((mb*16 + (lane & 15)) << 7) + (tb ^ swz));
    #pragma unroll
    for (int nb = 0; nb < 4; ++nb)
      Bv[nb] = *(const half8*)(tp + 8192 + ((nb*16 + (lane & 15)) << 7) + (tb ^ swz));
    #pragma unroll
    for (int mb = 0; mb < 4; ++mb)
      #pragma unroll
      for (int nb = 0; nb < 4; ++nb)
        acc[mb][nb] = __builtin_amdgcn_mfma_f32_16x16x32_f16(Av[mb], Bv[nb], acc[mb][nb], 0, 0, 0);
  }
  __syncthreads();
  const int m0 = (lane >> 4) << 2, n0 = lane & 15;
  #pragma unroll
  for (int mb = 0; mb < 4; ++mb)
    #pragma unroll
    for (int nb = 0; nb < 4; ++nb)
      #pragma unroll
      for (int r = 0; r < 4; ++r)
        atomicAdd(&red[(mb*16 + m0 + r)*64 + nb*16 + n0], acc[mb][nb][r]);
  __syncthreads();
  for (int i = tid; i < 4096; i += 256) atomicAdd(&Cpair[i], red[i]);
}

// ---------------- k5a: reduce cpart chunks + H_cond rows ----------------
__global__ __launch_bounds__(256) void vq_k5a(const float* __restrict__ cpart, float* __restrict__ hcond)
{
  __shared__ float srow[64][65];
  const int bx = blockIdx.x, tid = threadIdx.x;   // bx = k (64 rows of C)
  f32x4 a[4];
  #pragma unroll
  for (int j = 0; j < 4; ++j) a[j] = (f32x4)(0.f);
  #pragma unroll
  for (int cc = 0; cc < 16; ++cc) {
    const f32x4* src = (const f32x4*)(cpart + (size_t)cc*262144 + (size_t)bx*4096);
    #pragma unroll
    for (int j = 0; j < 4; ++j) a[j] += src[tid + j*256];
  }
  #pragma unroll
  for (int j = 0; j < 4; ++j) {
    int e = (tid + j*256) * 4;
    *(f32x4*)&srow[e >> 6][e & 63] = a[j];
  }
  __syncthreads();
  const int p = tid >> 2, qr = (tid & 3) * 16;
  float rs = 0.f;
  #pragma unroll
  for (int n = 0; n < 16; ++n) rs += srow[p][qr + n] + 0.001f;
  rs += __shfl_xor(rs, 1);
  rs += __shfl_xor(rs, 2);
  float inv = 1.0f / (rs + 1e-8f);
  float h = 0.f;
  #pragma unroll
  for (int n = 0; n < 16; ++n) {
    float T = (srow[p][qr + n] + 0.001f) * inv;
    h -= T * logf(T + 1e-8f);
  }
  h += __shfl_xor(h, 1);
  h += __shfl_xor(h, 2);
  if ((tid & 3) == 0) hcond[bx*64 + p] = h;
}

// ---------------- k5b: final scalar ----------------
__global__ __launch_bounds__(256) void vq_k5b(const float* __restrict__ Cpair, const float* __restrict__ hcond,
                                              const float* __restrict__ ghist2, const double* __restrict__ gmse2,
                                              const float* __restrict__ prior, float* __restrict__ out_loss)
{
  __shared__ float red[8];
  __shared__ float hsum[64];
  __shared__ double msh;
  const int tid = threadIdx.x;
  if (tid < 64) {
    float s = 0.f;
    #pragma unroll
    for (int c2 = 0; c2 < 16; ++c2) s += ghist2[(c2 << 6) + tid];
    hsum[tid] = s;
  }
  if (tid == 64) {
    double s = 0.0;
    for (int c2 = 0; c2 < 16; ++c2) s += gmse2[c2];
    msh = s;
  }
  float ts = 0.f, hh = 0.f;
  for (int p = tid; p < 4096; p += 256) {
    float cp = Cpair[p];
    ts += cp; hh += cp * hcond[p];
  }
  #pragma unroll
  for (int off = 32; off; off >>= 1) {
    ts += __shfl_down(ts, off);
    hh += __shfl_down(hh, off);
  }
  if ((tid & 63) == 0) { red[tid >> 6] = ts; red[4 + (tid >> 6)] = hh; }
  __syncthreads();
  if (tid == 0) {
    float total = red[0] + red[1] + red[2] + red[3];
    float H2 = (red[4] + red[5] + red[6] + red[7]) / (total + 1e-8f);
    float kl = 0.f;
    for (int kq = 0; kq < 64; ++kq) {
      float pk = hsum[kq] * (1.0f / 16384.0f);
      kl += pk * (logf(pk + 1e-10f) - logf(prior[kq] + 1e-10f));
    }
    float mse = (float)(msh * (1.0 / (16384.0 * 128.0)));
    out_loss[0] = 1.25f * mse + kl + 0.1f * H2;
  }
}

extern "C" void kernel_launch(void* const* d_in, const int* in_sizes, int n_in,
                              void* d_out, int out_size, void* d_ws, size_t ws_size,
                              hipStream_t stream)
{
  (void)in_sizes; (void)n_in; (void)out_size; (void)ws_size;
  const float* x     = (const float*)d_in[0];
  const float* emb   = (const float*)d_in[2];
  const float* prior = (const float*)d_in[3];
  float* quant    = (float*)d_out;
  float* loss_out = (float*)d_out + 2097152;

  char* ws = (char*)d_ws;
  unsigned short* qbf    = (unsigned short*)(ws);              // 256*24576 = 6,291,456 B
  float*          cpart  = (float*)(ws + 6291456);             // 16*64*4096*4 = 16,777,216 B
  float*          Cpair  = (float*)(ws + 23068672);            // 16,384 B
  double*         gmse2  = (double*)(ws + 23085056);           // 128 B
  float*          ghist2 = (float*)(ws + 23085184);            // 4,096 B  (end 23,089,280)
  float*          hcond  = (float*)(ws);                       // aliases qbf (dead after k3)

  hipMemsetAsync(ws + 23068672, 0, 20608, stream);             // Cpair + gmse2 + ghist2
  vq_k1 <<<256, 512, 0, stream>>>(x, emb, qbf, quant, ghist2, gmse2);
  vq_k2 <<<512, 256, 0, stream>>>(qbf, cpart);
  vq_k3 <<<64,  256, 0, stream>>>(qbf, Cpair);
  vq_k5a<<<64,  256, 0, stream>>>(cpart, hcond);
  vq_k5b<<<1,   256, 0, stream>>>(Cpair, hcond, ghist2, gmse2, prior, loss_out);
}

// Round 4
// 94.567 us; speedup vs baseline: 3.2310x; 1.0330x over previous
//
#include <hip/hip_runtime.h>
#include <cstdint>

#define NROWS 16384

typedef __attribute__((ext_vector_type(4))) float f32x4;
typedef _Float16 half8 __attribute__((ext_vector_type(8)));

static __device__ __forceinline__ void gl_lds16(const void* g, void* l) {
  __builtin_amdgcn_global_load_lds(
      (const __attribute__((address_space(1))) unsigned int*)g,
      (__attribute__((address_space(3))) unsigned int*)l, 16, 0, 0);
}

// ---------------- k1: distances/argmin/softmax/quantize + fp16 image build ----------------
// Block c owns rows 64c..64c+65 (2 halo rows recomputed); emits 3 shifted transposed
// swizzled fp16 images (24576 B per tile) consumed by k23. No global atomics:
// per-block hist/mse partial slots.
__global__ __launch_bounds__(512) void vq_k1(
    const float* __restrict__ x, const float* __restrict__ emb,
    unsigned short* __restrict__ qbf, float* __restrict__ quant,
    float* __restrict__ ghist_part, double* __restrict__ gmse_part)
{
  __shared__ float Et4[32][64][4];   // Et4[g][k][j] = emb[k][4g+j]
  __shared__ float xs[8][4][128];
  __shared__ float qlds[66][65];
  __shared__ float lhist[64];
  __shared__ double mred[8];
  const int tid = threadIdx.x;
  const int w = tid >> 6, lane = tid & 63;
  const int c = blockIdx.x;

  for (int i = tid; i < 2048; i += 512) {
    float4 v = ((const float4*)emb)[i];
    *(float4*)&Et4[i & 31][i >> 5][0] = v;
  }
  if (tid < 64) lhist[tid] = 0.0f;
  __syncthreads();

  double esq = 0.0;
  for (int g = 0; g < 32; ++g) {
    float4 e = *(float4*)&Et4[g][lane][0];
    esq += (double)e.x*e.x + (double)e.y*e.y + (double)e.z*e.z + (double)e.w*e.w;
  }
  const float esqf = (float)esq;

  double msea = 0.0;

  for (int it = 0; it < 3; ++it) {
    const int lr0 = it*32 + w*4;
    const bool act = (it < 2) || (w == 0);
    if (!act) continue;
    const int nr = (it < 2) ? 4 : 2;
    const int r0 = c*64 + lr0;
    const float4* xg = (const float4*)(x + (size_t)r0 * 128);
    if (it < 2) {
      float4 v0 = xg[lane], v1 = xg[lane + 64];
      *(float4*)&xs[w][lane>>5][(lane&31)<<2] = v0;
      *(float4*)&xs[w][2+(lane>>5)][(lane&31)<<2] = v1;
    } else {
      int rr = lane >> 5;
      float4 v0 = make_float4(0.f,0.f,0.f,0.f);
      if (r0 + rr < NROWS) v0 = xg[lane];
      *(float4*)&xs[w][rr][(lane&31)<<2] = v0;
    }

    float accf[4] = {0.f,0.f,0.f,0.f};
    for (int g = 0; g < 32; ++g) {
      float4 e = *(float4*)&Et4[g][lane][0];
      #pragma unroll
      for (int rr = 0; rr < 4; ++rr) {
        float4 xv = *(float4*)&xs[w][rr][g<<2];
        accf[rr] += e.x*xv.x + e.y*xv.y + e.z*xv.z + e.w*xv.w;
      }
    }

    for (int rr = 0; rr < nr; ++rr) {
      float dist = esqf - 2.0f*accf[rr];
      float mx = dist;
      #pragma unroll
      for (int off = 32; off; off >>= 1) mx = fmaxf(mx, __shfl_xor(mx, off));
      float sh = dist - mx;
      float ss = expf(sh);
      #pragma unroll
      for (int off = 32; off; off >>= 1) ss += __shfl_xor(ss, off);
      qlds[lr0 + rr][lane] = sh - logf(ss);

      if (it < 2) {
        // top-2 argmin butterfly (f32) with f64 fallback on near-tie
        float m1 = dist, m2 = 3.4e38f; int i1 = lane;
        #pragma unroll
        for (int off = 32; off; off >>= 1) {
          float om1 = __shfl_xor(m1, off);
          int   oi1 = __shfl_xor(i1, off);
          float om2 = __shfl_xor(m2, off);
          float nm2 = fminf(m2, om2);
          if (om1 < m1 || (om1 == m1 && oi1 < i1)) { nm2 = fminf(nm2, m1); m1 = om1; i1 = oi1; }
          else nm2 = fminf(nm2, om1);
          m2 = nm2;
        }
        int bi = i1;
        if (m2 - m1 < 1e-4f) {
          double a64 = 0.0;
          for (int g = 0; g < 32; ++g) {
            float4 e = *(float4*)&Et4[g][lane][0];
            float4 xv = *(float4*)&xs[w][rr][g<<2];
            a64 += (double)e.x*xv.x + (double)e.y*xv.y + (double)e.z*xv.z + (double)e.w*xv.w;
          }
          double v = esq - 2.0*a64; int b2 = lane;
          #pragma unroll
          for (int off = 32; off; off >>= 1) {
            double ov = __shfl_xor(v, off);
            int ob = __shfl_xor(b2, off);
            if (ov < v || (ov == v && ob < b2)) { v = ov; b2 = ob; }
          }
          bi = b2;
        }
        const int row = r0 + rr;
        float e0 = emb[bi*128 + lane], e1 = emb[bi*128 + 64 + lane];
        float x0 = xs[w][rr][lane], x1 = xs[w][rr][64 + lane];
        quant[(size_t)row*128 + lane]      = x0 + (e0 - x0);
        quant[(size_t)row*128 + 64 + lane] = x1 + (e1 - x1);
        double d0 = (double)e0 - x0, d1 = (double)e1 - x1;
        msea += d0*d0 + d1*d1;
        if (lane == 0) atomicAdd(&lhist[bi], 1.0f);
      }
    }
  }
  #pragma unroll
  for (int off = 32; off; off >>= 1) msea += __shfl_down(msea, off);
  if (lane == 0) mred[w] = msea;
  __syncthreads();
  if (tid == 0) {
    double s = 0.0;
    #pragma unroll
    for (int j = 0; j < 8; ++j) s += mred[j];
    gmse_part[c] = s;
  }
  if (tid < 64) ghist_part[(c << 6) + tid] = lhist[tid];

  // image build: im_s[kk][tt] = q[64c+tt+s][kk], fp16, XOR-swizzled, boundary-zeroed
  char* out0 = (char*)qbf + (size_t)c * 24576;
  for (int idx = tid; idx < 1536; idx += 512) {
    int s = idx >> 9, kk = (idx >> 3) & 63, t8 = (idx & 7) << 3;
    union { _Float16 h[8]; uint4 u; } pk;
    #pragma unroll
    for (int j = 0; j < 8; ++j) {
      int tt = t8 + j, t = c*64 + tt;
      float val = qlds[tt + s][kk];
      bool zero = (s == 1 && (t & 4095) == 4095) || (s == 2 && (t & 4095) >= 4094);
      pk.h[j] = (_Float16)(zero ? 0.0f : val);
    }
    *(uint4*)(out0 + s*8192 + kk*128 + ((t8*2) ^ ((kk & 7) << 4))) = pk.u;
  }
}

// ---------------- k23: C partials (blocks 0..511) + C_pair partials (blocks 512..527) ----------------
__global__ __launch_bounds__(256) void vq_k23(const unsigned short* __restrict__ qbf,
                                              float* __restrict__ cpart, float* __restrict__ ppart)
{
  __shared__ __align__(16) char ldsbuf[32768];
  const int bx = blockIdx.x;
  const int tid = threadIdx.x;
  const int w = tid >> 6, lane = tid & 63;

  if (bx < 512) {
    // ---- triple-einsum partials: kg(32) x chunk(16); waves: klocal(2) x s-half(2)
    const int kg = bx >> 4, chunk = bx & 15;
    const int klocal = w >> 1, s = w & 1;
    const int k = kg*2 + klocal;

    f32x4 acc[4][4];
    #pragma unroll
    for (int i = 0; i < 4; ++i)
      #pragma unroll
      for (int j = 0; j < 4; ++j) acc[i][j] = (f32x4)(0.f);

    const char* qb = (const char*)qbf;
    const int t0 = chunk * 16;
    const int tb = (s << 6) | ((lane >> 4) << 4);
    const int swz = (lane & 7) << 4;
    const int swzk = (k & 7) << 4;

    {
      const char* src = qb + (size_t)t0 * 24576 + 8192 + w*4096 + lane*16;
      char* dst = ldsbuf + w*4096;
      #pragma unroll
      for (int j = 0; j < 4; ++j) gl_lds16(src + j*1024, dst + j*1024);
    }
    half8 q0v = *(const half8*)(qb + (size_t)t0 * 24576 + (k << 7) + (tb ^ swzk));

    int cur = 0;
    for (int i = 0; i < 16; ++i) {
      half8 q0n = q0v;
      if (i < 15) {
        const char* src = qb + (size_t)(t0+i+1) * 24576 + 8192 + w*4096 + lane*16;
        char* dst = ldsbuf + (cur^1)*16384 + w*4096;
        #pragma unroll
        for (int j = 0; j < 4; ++j) gl_lds16(src + j*1024, dst + j*1024);
        q0n = *(const half8*)(qb + (size_t)(t0+i+1) * 24576 + (k << 7) + (tb ^ swzk));
        asm volatile("s_waitcnt vmcnt(5)" ::: "memory");
      } else {
        asm volatile("s_waitcnt vmcnt(0)" ::: "memory");
      }
      __builtin_amdgcn_s_barrier();
      __builtin_amdgcn_sched_barrier(0);

      const char* base = ldsbuf + cur*16384;   // [0,8K)=im1, [8K,16K)=im2
      half8 Bv[4], q1v[4];
      #pragma unroll
      for (int nb = 0; nb < 4; ++nb)
        Bv[nb] = *(const half8*)(base + 8192 + ((nb*16 + (lane & 15)) << 7) + (tb ^ swz));
      #pragma unroll
      for (int mb = 0; mb < 4; ++mb)
        q1v[mb] = *(const half8*)(base + ((mb*16 + (lane & 15)) << 7) + (tb ^ swz));
      #pragma unroll
      for (int mb = 0; mb < 4; ++mb) {
        half8 av = q0v * q1v[mb];              // v_pk_mul_f16 x4
        #pragma unroll
        for (int nb = 0; nb < 4; ++nb)
          acc[mb][nb] = __builtin_amdgcn_mfma_f32_16x16x32_f16(av, Bv[nb], acc[mb][nb], 0, 0, 0);
      }
      __builtin_amdgcn_sched_barrier(0);
      __builtin_amdgcn_s_barrier();
      q0v = q0n;
      cur ^= 1;
    }

    __syncthreads();
    float* red = (float*)ldsbuf;               // 2 x 4096 f32
    const int m0 = (lane >> 4) << 2, n0 = lane & 15;
    if (s == 0) {
      #pragma unroll
      for (int mb = 0; mb < 4; ++mb)
        #pragma unroll
        for (int nb = 0; nb < 4; ++nb)
          #pragma unroll
          for (int r = 0; r < 4; ++r)
            red[klocal*4096 + (mb*16 + m0 + r)*64 + nb*16 + n0] = acc[mb][nb][r];
    }
    __syncthreads();
    if (s == 1) {
      #pragma unroll
      for (int mb = 0; mb < 4; ++mb)
        #pragma unroll
        for (int nb = 0; nb < 4; ++nb)
          #pragma unroll
          for (int r = 0; r < 4; ++r)
            red[klocal*4096 + (mb*16 + m0 + r)*64 + nb*16 + n0] += acc[mb][nb][r];
    }
    __syncthreads();
    float* dst = cpart + ((size_t)chunk*64 + (size_t)kg*2) * 4096;
    for (int i2 = tid; i2 < 2048; i2 += 256)
      ((f32x4*)dst)[i2] = ((const f32x4*)red)[i2];
  } else {
    // ---- pair-einsum partials: 16 blocks x 4 waves x 4 tiles
    const int bx2 = bx - 512;
    float* red = (float*)ldsbuf;               // 4096 f32
    for (int i = tid; i < 4096; i += 256) red[i] = 0.f;

    f32x4 acc[4][4];
    #pragma unroll
    for (int i = 0; i < 4; ++i)
      #pragma unroll
      for (int j = 0; j < 4; ++j) acc[i][j] = (f32x4)(0.f);

    for (int ii = 0; ii < 4; ++ii) {
      const char* tp = (const char*)qbf + (size_t)(bx2*16 + w*4 + ii) * 24576;
      #pragma unroll
      for (int s = 0; s < 2; ++s) {
        const int tb = (s << 6) | ((lane >> 4) << 4);
        const int swz = (lane & 7) << 4;
        half8 Av[4], Bv[4];
        #pragma unroll
        for (int mb = 0; mb < 4; ++mb)
          Av[mb] = *(const half8*)(tp + ((mb*16 + (lane & 15)) << 7) + (tb ^ swz));
        #pragma unroll
        for (int nb = 0; nb < 4; ++nb)
          Bv[nb] = *(const half8*)(tp + 8192 + ((nb*16 + (lane & 15)) << 7) + (tb ^ swz));
        #pragma unroll
        for (int mb = 0; mb < 4; ++mb)
          #pragma unroll
          for (int nb = 0; nb < 4; ++nb)
            acc[mb][nb] = __builtin_amdgcn_mfma_f32_16x16x32_f16(Av[mb], Bv[nb], acc[mb][nb], 0, 0, 0);
      }
    }
    __syncthreads();
    const int m0 = (lane >> 4) << 2, n0 = lane & 15;
    #pragma unroll
    for (int mb = 0; mb < 4; ++mb)
      #pragma unroll
      for (int nb = 0; nb < 4; ++nb)
        #pragma unroll
        for (int r = 0; r < 4; ++r)
          atomicAdd(&red[(mb*16 + m0 + r)*64 + nb*16 + n0], acc[mb][nb][r]);
    __syncthreads();
    float* dst = ppart + (size_t)bx2 * 4096;
    for (int i = tid; i < 4096; i += 256) dst[i] = red[i];
  }
}

// ---------------- k5a: reduce cpart chunks + H_cond rows ----------------
__global__ __launch_bounds__(256) void vq_k5a(const float* __restrict__ cpart, float* __restrict__ hcond)
{
  __shared__ float srow[64][65];
  const int bx = blockIdx.x, tid = threadIdx.x;   // bx = k (64 rows of C)
  f32x4 a[4];
  #pragma unroll
  for (int j = 0; j < 4; ++j) a[j] = (f32x4)(0.f);
  #pragma unroll
  for (int cc = 0; cc < 16; ++cc) {
    const f32x4* src = (const f32x4*)(cpart + (size_t)cc*262144 + (size_t)bx*4096);
    #pragma unroll
    for (int j = 0; j < 4; ++j) a[j] += src[tid + j*256];
  }
  #pragma unroll
  for (int j = 0; j < 4; ++j) {
    int e = (tid + j*256) * 4;
    *(f32x4*)&srow[e >> 6][e & 63] = a[j];
  }
  __syncthreads();
  const int p = tid >> 2, qr = (tid & 3) * 16;
  float rs = 0.f;
  #pragma unroll
  for (int n = 0; n < 16; ++n) rs += srow[p][qr + n] + 0.001f;
  rs += __shfl_xor(rs, 1);
  rs += __shfl_xor(rs, 2);
  float inv = 1.0f / (rs + 1e-8f);
  float h = 0.f;
  #pragma unroll
  for (int n = 0; n < 16; ++n) {
    float T = (srow[p][qr + n] + 0.001f) * inv;
    h -= T * logf(T + 1e-8f);
  }
  h += __shfl_xor(h, 1);
  h += __shfl_xor(h, 2);
  if ((tid & 3) == 0) hcond[bx*64 + p] = h;
}

// ---------------- k5b: final scalar ----------------
__global__ __launch_bounds__(256) void vq_k5b(const float* __restrict__ ppart, const float* __restrict__ hcond,
                                              const float* __restrict__ ghist_part, const double* __restrict__ gmse_part,
                                              const float* __restrict__ prior, float* __restrict__ out_loss)
{
  __shared__ float red[8];
  __shared__ float hsum[64];
  __shared__ double msh;
  const int tid = threadIdx.x;
  if (tid < 64) {
    float s = 0.f;
    for (int c2 = 0; c2 < 256; ++c2) s += ghist_part[(c2 << 6) + tid];
    hsum[tid] = s;
  }
  if (tid == 64) {
    double s = 0.0;
    for (int c2 = 0; c2 < 256; ++c2) s += gmse_part[c2];
    msh = s;
  }
  float ts = 0.f, hh = 0.f;
  for (int p = tid; p < 4096; p += 256) {
    float cp = 0.f;
    #pragma unroll
    for (int cc = 0; cc < 16; ++cc) cp += ppart[cc*4096 + p];
    ts += cp; hh += cp * hcond[p];
  }
  #pragma unroll
  for (int off = 32; off; off >>= 1) {
    ts += __shfl_down(ts, off);
    hh += __shfl_down(hh, off);
  }
  if ((tid & 63) == 0) { red[tid >> 6] = ts; red[4 + (tid >> 6)] = hh; }
  __syncthreads();
  if (tid == 0) {
    float total = red[0] + red[1] + red[2] + red[3];
    float H2 = (red[4] + red[5] + red[6] + red[7]) / (total + 1e-8f);
    float kl = 0.f;
    for (int kq = 0; kq < 64; ++kq) {
      float pk = hsum[kq] * (1.0f / 16384.0f);
      kl += pk * (logf(pk + 1e-10f) - logf(prior[kq] + 1e-10f));
    }
    float mse = (float)(msh * (1.0 / (16384.0 * 128.0)));
    out_loss[0] = 1.25f * mse + kl + 0.1f * H2;
  }
}

extern "C" void kernel_launch(void* const* d_in, const int* in_sizes, int n_in,
                              void* d_out, int out_size, void* d_ws, size_t ws_size,
                              hipStream_t stream)
{
  (void)in_sizes; (void)n_in; (void)out_size; (void)ws_size;
  const float* x     = (const float*)d_in[0];
  const float* emb   = (const float*)d_in[2];
  const float* prior = (const float*)d_in[3];
  float* quant    = (float*)d_out;
  float* loss_out = (float*)d_out + 2097152;

  char* ws = (char*)d_ws;
  unsigned short* qbf        = (unsigned short*)(ws);           // 256*24576 = 6,291,456 B
  float*          cpart      = (float*)(ws + 6291456);          // 16*64*4096*4 = 16,777,216 B
  float*          ppart      = (float*)(ws + 23068672);         // 16*4096*4 = 262,144 B
  float*          ghist_part = (float*)(ws + 23330816);         // 256*64*4 = 65,536 B
  double*         gmse_part  = (double*)(ws + 23396352);        // 256*8 = 2,048 B
  float*          hcond      = (float*)(ws + 23398400);         // 16,384 B

  vq_k1 <<<256, 512, 0, stream>>>(x, emb, qbf, quant, ghist_part, gmse_part);
  vq_k23<<<528, 256, 0, stream>>>(qbf, cpart, ppart);
  vq_k5a<<<64,  256, 0, stream>>>(cpart, hcond);
  vq_k5b<<<1,   256, 0, stream>>>(ppart, hcond, ghist_part, gmse_part, prior, loss_out);
}